// Round 2
// baseline (5307.649 us; speedup 1.0000x reference)
//
#include <hip/hip_runtime.h>
#include <hip/hip_bf16.h>
#include <math.h>

#define NN 50000
#define EE 200000
#define ET 250000   // EE + NN self loops
#define GG 64
#define LL 6

__device__ __forceinline__ float elu1(float x) { return x > 0.f ? x : expm1f(x); }
__device__ __forceinline__ float gelu_exact(float x) {
    return 0.5f * x * (1.f + erff(x * 0.70710678118654752440f));
}
__device__ __forceinline__ float bflo(unsigned int w) { return __uint_as_float(w << 16); }
__device__ __forceinline__ float bfhi(unsigned int w) { return __uint_as_float(w & 0xffff0000u); }

// ---------------- CSR build ----------------
__global__ void count_deg_kernel(const int* __restrict__ ei, int* __restrict__ deg) {
    int e = blockIdx.x * 256 + threadIdx.x;
    if (e >= ET) return;
    int dst = (e < EE) ? ei[EE + e] : (e - EE);
    atomicAdd(&deg[dst], 1);
}

__global__ void scan_kernel(const int* __restrict__ deg, int* __restrict__ row_ptr, int n) {
    __shared__ int sdata[1024];
    __shared__ int carry;
    if (threadIdx.x == 0) carry = 0;
    __syncthreads();
    for (int base = 0; base < n; base += 1024) {
        int i = base + threadIdx.x;
        int v = (i < n) ? deg[i] : 0;
        sdata[threadIdx.x] = v;
        __syncthreads();
        for (int off = 1; off < 1024; off <<= 1) {
            int t = (threadIdx.x >= off) ? sdata[threadIdx.x - off] : 0;
            __syncthreads();
            if (threadIdx.x >= off) sdata[threadIdx.x] += t;
            __syncthreads();
        }
        int incl = sdata[threadIdx.x];
        if (i < n) row_ptr[i] = carry + incl - v;   // exclusive
        __syncthreads();
        if (threadIdx.x == 1023) carry += sdata[1023];
        __syncthreads();
    }
    if (threadIdx.x == 0) row_ptr[n] = carry;
}

__global__ void fill_csr_kernel(const int* __restrict__ ei, const int* __restrict__ row_ptr,
                                int* __restrict__ cursor, int* __restrict__ edge_src) {
    int e = blockIdx.x * 256 + threadIdx.x;
    if (e >= ET) return;
    int src, dst;
    if (e < EE) { src = ei[e]; dst = ei[EE + e]; }
    else        { src = e - EE; dst = e - EE; }
    int pos = atomicAdd(&cursor[dst], 1);
    edge_src[row_ptr[dst] + pos] = src;
}

__global__ void dinv_kernel(const int* __restrict__ row_ptr, float* __restrict__ dinv) {
    int n = blockIdx.x * 256 + threadIdx.x;
    if (n >= NN) return;
    int d = row_ptr[n + 1] - row_ptr[n];
    dinv[n] = (d > 0) ? rsqrtf((float)d) : 0.f;
}

// ---------------- GEMM: C[M,Nc] = A[M,K] @ B[K,Nc] (+bias)(+act) ----------------
// A fp32 or bf16 (ABF16), B fp32 with leading dim ldb, C fp32 with leading dim ldc.
// 128x128 tile, BK=16, 8x8 outputs/thread, 256 threads.
template <bool ABF16, bool BIAS, int ACT>
__global__ __launch_bounds__(256) void gemm_kernel(
    const void* __restrict__ Av, const float* __restrict__ B,
    const float* __restrict__ bias, float* __restrict__ C,
    int M, int K, int Nc, int ldb, int ldc) {
    __shared__ float As[16][128];
    __shared__ float Bs[16][128];
    int t = threadIdx.x;
    int bm = blockIdx.x * 128, bn = blockIdx.y * 128;
    int tx = t & 15, ty = t >> 4;     // 16x16 threads, each 8x8 outputs
    float acc[8][8];
#pragma unroll
    for (int i = 0; i < 8; i++)
#pragma unroll
        for (int j = 0; j < 8; j++) acc[i][j] = 0.f;

    int arow = t & 127;        // A-load row within tile
    int ak0  = (t >> 7) * 8;   // A-load k offset (0 or 8)
    int bkr  = t >> 4;         // B-load k row (0..15)
    int bnv  = t & 15;         // B-load col group

    for (int k0 = 0; k0 < K; k0 += 16) {
        int gr = bm + arow;
        float av[8];
        if (gr < M) {
            if (ABF16) {
                const unsigned short* Ab = (const unsigned short*)Av;
                uint4 u = *(const uint4*)(Ab + (size_t)gr * K + k0 + ak0);
                av[0] = bflo(u.x); av[1] = bfhi(u.x);
                av[2] = bflo(u.y); av[3] = bfhi(u.y);
                av[4] = bflo(u.z); av[5] = bfhi(u.z);
                av[6] = bflo(u.w); av[7] = bfhi(u.w);
            } else {
                const float* Af = (const float*)Av;
                float4 v0 = *(const float4*)(Af + (size_t)gr * K + k0 + ak0);
                float4 v1 = *(const float4*)(Af + (size_t)gr * K + k0 + ak0 + 4);
                av[0] = v0.x; av[1] = v0.y; av[2] = v0.z; av[3] = v0.w;
                av[4] = v1.x; av[5] = v1.y; av[6] = v1.z; av[7] = v1.w;
            }
        } else {
#pragma unroll
            for (int j = 0; j < 8; j++) av[j] = 0.f;
        }
#pragma unroll
        for (int j = 0; j < 8; j++) As[ak0 + j][arow] = av[j];
        {
            const float* Bp = B + (size_t)(k0 + bkr) * ldb + bn + bnv * 8;
            float4 v0 = *(const float4*)(Bp);
            float4 v1 = *(const float4*)(Bp + 4);
            *(float4*)&Bs[bkr][bnv * 8] = v0;
            *(float4*)&Bs[bkr][bnv * 8 + 4] = v1;
        }
        __syncthreads();
#pragma unroll
        for (int k = 0; k < 16; k++) {
            float a[8], b[8];
            *(float4*)&a[0] = *(const float4*)&As[k][ty * 8];
            *(float4*)&a[4] = *(const float4*)&As[k][ty * 8 + 4];
            *(float4*)&b[0] = *(const float4*)&Bs[k][tx * 8];
            *(float4*)&b[4] = *(const float4*)&Bs[k][tx * 8 + 4];
#pragma unroll
            for (int i = 0; i < 8; i++)
#pragma unroll
                for (int j = 0; j < 8; j++) acc[i][j] += a[i] * b[j];
        }
        __syncthreads();
    }
#pragma unroll
    for (int i = 0; i < 8; i++) {
        int gr = bm + ty * 8 + i;
        if (gr >= M) continue;
        float* Cp = C + (size_t)gr * ldc + bn + tx * 8;
        float vv[8];
#pragma unroll
        for (int j = 0; j < 8; j++) {
            float v = acc[i][j];
            if (BIAS) v += bias[bn + tx * 8 + j];
            if (ACT == 1) v = gelu_exact(v);
            vv[j] = v;
        }
        *(float4*)(Cp)     = *(float4*)&vv[0];
        *(float4*)(Cp + 4) = *(float4*)&vv[4];
    }
}

// ---------------- per-node attention scalars for one head chunk [N,128] -------
__global__ __launch_bounds__(256) void asad_c_kernel(
    const float* __restrict__ hpre, const float* __restrict__ a_s,
    const float* __restrict__ a_d, float* __restrict__ as_, float* __restrict__ ad_,
    int n_nodes) {
    int node = blockIdx.x * 4 + (threadIdx.x >> 6);
    int lane = threadIdx.x & 63;
    if (node >= n_nodes) return;
    const float* hp = hpre + (size_t)node * 128;
    float h0 = hp[lane], h1 = hp[lane + 64];
    float vs = h0 * a_s[lane] + h1 * a_s[lane + 64];
    float vd = h0 * a_d[lane] + h1 * a_d[lane + 64];
    for (int o = 32; o > 0; o >>= 1) { vs += __shfl_xor(vs, o); vd += __shfl_xor(vd, o); }
    if (lane == 0) { as_[node] = vs; ad_[node] = vd; }
}

// ---- GAT softmax-aggregate for one head chunk; writes bf16 column block ------
__global__ __launch_bounds__(256) void gat_agg_c_kernel(
    const float* __restrict__ hpre, const float* __restrict__ as_,
    const float* __restrict__ ad_, const float* __restrict__ bias,
    const int* __restrict__ row_ptr, const int* __restrict__ edge_src,
    __hip_bfloat16* __restrict__ out, int ostride, int n_nodes) {
    int node = blockIdx.x * 2 + (threadIdx.x >> 7);
    int c = threadIdx.x & 127;
    if (node >= n_nodes) return;
    int start = row_ptr[node];
    int deg = row_ptr[node + 1] - start;
    float adn = ad_[node];
    float m = -1e30f;
    for (int j = 0; j < deg; j++) {
        int s = edge_src[start + j];
        float e = as_[s] + adn;
        e = e > 0.f ? e : 0.2f * e;
        m = fmaxf(m, e);
    }
    float ssum = 0.f;
    for (int j = 0; j < deg; j++) {
        int s = edge_src[start + j];
        float e = as_[s] + adn;
        e = e > 0.f ? e : 0.2f * e;
        ssum += expf(e - m);
    }
    float inv = 1.f / (ssum + 1e-16f);
    float acc = 0.f;
    for (int j = 0; j < deg; j++) {
        int s = edge_src[start + j];
        float e = as_[s] + adn;
        e = e > 0.f ? e : 0.2f * e;
        acc += expf(e - m) * inv * hpre[(size_t)s * 128 + c];
    }
    out[(size_t)node * ostride + c] = __float2bfloat16(elu1(acc + bias[c]));
}

// ---------------- GCN aggregation (fp32 chunk in, fp32 out) ----------------
__global__ __launch_bounds__(256) void gcn_agg_kernel(
    const float* __restrict__ hp, const float* __restrict__ dinv,
    const float* __restrict__ b3, const int* __restrict__ row_ptr,
    const int* __restrict__ edge_src, float* __restrict__ out, int n_nodes) {
    int node = blockIdx.x * 2 + (threadIdx.x >> 7);
    int c = threadIdx.x & 127;
    if (node >= n_nodes) return;
    int start = row_ptr[node];
    int deg = row_ptr[node + 1] - start;
    float dn = dinv[node];
    float acc = 0.f;
    for (int j = 0; j < deg; j++) {
        int s = edge_src[start + j];
        acc += dinv[s] * dn * hp[(size_t)s * 128 + c];
    }
    out[(size_t)node * 128 + c] = elu1(acc + b3[c]);
}

// ---------------- residual + LayerNorm (in place into Q) ----------------
__global__ __launch_bounds__(256) void ln_residual_kernel(
    float* __restrict__ Q, const float* __restrict__ R,
    const float* __restrict__ g, const float* __restrict__ b, int n_nodes) {
    int node = blockIdx.x * 4 + (threadIdx.x >> 6);
    int lane = threadIdx.x & 63;
    if (node >= n_nodes) return;
    size_t base = (size_t)node * 128;
    float v0 = Q[base + lane] + R[base + lane];
    float v1 = Q[base + 64 + lane] + R[base + 64 + lane];
    float s = v0 + v1;
    for (int o = 32; o > 0; o >>= 1) s += __shfl_xor(s, o);
    float mean = s * (1.f / 128.f);
    float d0 = v0 - mean, d1 = v1 - mean;
    float vv = d0 * d0 + d1 * d1;
    for (int o = 32; o > 0; o >>= 1) vv += __shfl_xor(vv, o);
    float rstd = rsqrtf(vv * (1.f / 128.f) + 1e-5f);
    Q[base + lane]      = d0 * rstd * g[lane] + b[lane];
    Q[base + 64 + lane] = d1 * rstd * g[lane + 64] + b[lane + 64];
}

// ---------------- pooling (mean/max per graph) + BN1 ----------------
__global__ void pool_kernel(const float* __restrict__ Q, const int* __restrict__ batch,
                            const float* __restrict__ bn1g, const float* __restrict__ bn1b,
                            float* __restrict__ hc, int n_nodes) {
    int g = blockIdx.x;
    int c = threadIdx.x;  // 128 threads
    int lo, hi;
    {
        int l = 0, h = n_nodes;
        while (l < h) { int mid = (l + h) >> 1; if (batch[mid] < g) l = mid + 1; else h = mid; }
        lo = l;
        l = lo; h = n_nodes;
        while (l < h) { int mid = (l + h) >> 1; if (batch[mid] < g + 1) l = mid + 1; else h = mid; }
        hi = l;
    }
    float s = 0.f, mx = -INFINITY;
    for (int n = lo; n < hi; n++) {
        float v = Q[(size_t)n * 128 + c];
        s += v;
        mx = fmaxf(mx, v);
    }
    int cnt = hi - lo;
    float hm = s / fmaxf((float)cnt, 1.f);
    float hx = (cnt > 0 && isfinite(mx)) ? mx : 0.f;
    const float bn_s = 0.99999500003749968f;  // 1/sqrt(1+1e-5)
    hc[g * 256 + c]       = hm * bn_s * bn1g[c] + bn1b[c];
    hc[g * 256 + 128 + c] = hx * bn_s * bn1g[128 + c] + bn1b[128 + c];
}

// ---------------- head: fc1+elu+bn2+fc2 ----------------
__global__ void head_kernel(const float* __restrict__ hc,
                            const float* __restrict__ fc1w, const float* __restrict__ fc1b,
                            const float* __restrict__ bn2g, const float* __restrict__ bn2b,
                            const float* __restrict__ fc2w, const float* __restrict__ fc2b,
                            float* __restrict__ out) {
    int g = blockIdx.x;
    int j = threadIdx.x;  // 64 threads
    const float bn_s = 0.99999500003749968f;
    float acc = fc1b[j];
    for (int i = 0; i < 256; i++) acc += hc[g * 256 + i] * fc1w[i * 64 + j];
    acc = elu1(acc);
    acc = acc * bn_s * bn2g[j] + bn2b[j];
    __shared__ float sv[64];
    sv[j] = acc;
    __syncthreads();
    if (j < 2) {
        float o = fc2b[j];
        for (int i = 0; i < 64; i++) o += sv[i] * fc2w[i * 2 + j];
        out[g * 2 + j] = o;
    }
}

// ---------------- launch ----------------
extern "C" void kernel_launch(void* const* d_in, const int* in_sizes, int n_in,
                              void* d_out, int out_size, void* d_ws, size_t ws_size,
                              hipStream_t stream) {
    const float* x    = (const float*)d_in[0];
    const int*   ei   = (const int*)d_in[1];
    const int*   batch= (const int*)d_in[2];
    const float* W1   = (const float*)d_in[3];
    const float* as1  = (const float*)d_in[4];
    const float* ad1  = (const float*)d_in[5];
    const float* b1   = (const float*)d_in[6];
    const float* W2   = (const float*)d_in[7];
    const float* as2  = (const float*)d_in[8];
    const float* ad2  = (const float*)d_in[9];
    const float* b2   = (const float*)d_in[10];
    const float* W3   = (const float*)d_in[11];
    const float* b3   = (const float*)d_in[12];
    const float* wv   = (const float*)d_in[17];
    const float* bv   = (const float*)d_in[18];
    const float* wo   = (const float*)d_in[19];
    const float* bo   = (const float*)d_in[20];
    const float* ln1g = (const float*)d_in[21];
    const float* ln1b = (const float*)d_in[22];
    const float* ln2g = (const float*)d_in[23];
    const float* ln2b = (const float*)d_in[24];
    const float* wf1  = (const float*)d_in[25];
    const float* bf1  = (const float*)d_in[26];
    const float* wf2  = (const float*)d_in[27];
    const float* bf2  = (const float*)d_in[28];
    const float* bn1g = (const float*)d_in[29];
    const float* bn1b = (const float*)d_in[30];
    const float* fc1w = (const float*)d_in[31];
    const float* fc1b = (const float*)d_in[32];
    const float* bn2g = (const float*)d_in[33];
    const float* bn2b = (const float*)d_in[34];
    const float* fc2w = (const float*)d_in[35];
    const float* fc2b = (const float*)d_in[36];
    float* out = (float*)d_out;

    // ---- workspace layout (bytes), peak ~233 MB ----
    char* wsb = (char*)d_ws;
    __hip_bfloat16* bh1 = (__hip_bfloat16*)wsb;                 // [N,1024] bf16 = 102.4 MB
    float* fFF = (float*)wsb;                                   // [N,512] fp32 overlay (h1 dead)
    __hip_bfloat16* bh2 = (__hip_bfloat16*)(wsb + 102400000);   // [N,512] bf16 = 51.2 MB
    float* fCh = (float*)(wsb + 153600000);                     // [N,128] fp32 chunk / h3pre / P
    float* fQ  = (float*)(wsb + 179200000);                     // [N,128] fp32
    float* fV  = (float*)(wsb + 204800000);                     // [N,128] fp32
    float* fAS = (float*)(wsb + 230400000);                     // [N]
    float* fAD = fAS + NN;                                      // [N]
    float* fDv = fAD + NN;                                      // [N]
    float* fHC = fDv + NN;                                      // [G,256]
    int* iDeg = (int*)(fHC + GG * 256);                         // [N]
    int* iRP  = iDeg + NN;                                      // [N+1]
    int* iCur = iRP + NN + 1;                                   // [N]
    int* iES  = iCur + NN;                                      // [ET]

    hipMemsetAsync(iDeg, 0, NN * sizeof(int), stream);
    hipMemsetAsync(iCur, 0, NN * sizeof(int), stream);

    count_deg_kernel<<<(ET + 255) / 256, 256, 0, stream>>>(ei, iDeg);
    scan_kernel<<<1, 1024, 0, stream>>>(iDeg, iRP, NN);
    fill_csr_kernel<<<(ET + 255) / 256, 256, 0, stream>>>(ei, iRP, iCur, iES);
    dinv_kernel<<<(NN + 255) / 256, 256, 0, stream>>>(iRP, fDv);

    auto gemm = [&](bool abf16, const void* A, const float* Bm, const float* bias, float* C,
                    int M, int K, int Ncol, int ldb, int ldc, int mode) {
        dim3 grid((M + 127) / 128, Ncol / 128);
        if (!abf16) {
            if (mode == 0)
                gemm_kernel<false, false, 0><<<grid, 256, 0, stream>>>(A, Bm, nullptr, C, M, K, Ncol, ldb, ldc);
            else if (mode == 1)
                gemm_kernel<false, true, 0><<<grid, 256, 0, stream>>>(A, Bm, bias, C, M, K, Ncol, ldb, ldc);
            else
                gemm_kernel<false, true, 1><<<grid, 256, 0, stream>>>(A, Bm, bias, C, M, K, Ncol, ldb, ldc);
        } else {
            if (mode == 0)
                gemm_kernel<true, false, 0><<<grid, 256, 0, stream>>>(A, Bm, nullptr, C, M, K, Ncol, ldb, ldc);
            else if (mode == 1)
                gemm_kernel<true, true, 0><<<grid, 256, 0, stream>>>(A, Bm, bias, C, M, K, Ncol, ldb, ldc);
            else
                gemm_kernel<true, true, 1><<<grid, 256, 0, stream>>>(A, Bm, bias, C, M, K, Ncol, ldb, ldc);
        }
    };

    // ---- GAT layer 1: 8 heads, chunked ----
    for (int h = 0; h < 8; h++) {
        gemm(false, x, W1 + h * 128, nullptr, fCh, NN, 128, 128, 1024, 128, 0);
        asad_c_kernel<<<(NN + 3) / 4, 256, 0, stream>>>(fCh, as1 + h * 128, ad1 + h * 128, fAS, fAD, NN);
        gat_agg_c_kernel<<<(NN + 1) / 2, 256, 0, stream>>>(fCh, fAS, fAD, b1 + h * 128, iRP, iES,
                                                           bh1 + h * 128, 1024, NN);
    }
    // ---- GAT layer 2: 4 heads, chunked, A = bf16 h1 ----
    for (int h = 0; h < 4; h++) {
        gemm(true, bh1, W2 + h * 128, nullptr, fCh, NN, 1024, 128, 512, 128, 0);
        asad_c_kernel<<<(NN + 3) / 4, 256, 0, stream>>>(fCh, as2 + h * 128, ad2 + h * 128, fAS, fAD, NN);
        gat_agg_c_kernel<<<(NN + 1) / 2, 256, 0, stream>>>(fCh, fAS, fAD, b2 + h * 128, iRP, iES,
                                                           bh2 + h * 128, 512, NN);
    }
    // ---- GCN ----
    gemm(true, bh2, W3, nullptr, fCh, NN, 512, 128, 128, 128, 0);
    gcn_agg_kernel<<<(NN + 1) / 2, 256, 0, stream>>>(fCh, fDv, b3, iRP, iES, fQ, NN);
    // ---- Transformer encoder (seq_len=1: attn == Wo(Wv h + bv) + bo) ----
    for (int l = 0; l < LL; l++) {
        gemm(false, fQ, wv + (size_t)l * 128 * 128, bv + l * 128, fV, NN, 128, 128, 128, 128, 1);
        gemm(false, fV, wo + (size_t)l * 128 * 128, bo + l * 128, fCh, NN, 128, 128, 128, 128, 1);
        ln_residual_kernel<<<(NN + 3) / 4, 256, 0, stream>>>(fQ, fCh, ln1g + l * 128, ln1b + l * 128, NN);
        gemm(false, fQ, wf1 + (size_t)l * 128 * 512, bf1 + l * 512, fFF, NN, 128, 512, 512, 512, 2);
        gemm(false, fFF, wf2 + (size_t)l * 512 * 128, bf2 + l * 128, fCh, NN, 512, 128, 128, 128, 1);
        ln_residual_kernel<<<(NN + 3) / 4, 256, 0, stream>>>(fQ, fCh, ln2g + l * 128, ln2b + l * 128, NN);
    }
    // ---- pool + head ----
    pool_kernel<<<GG, 128, 0, stream>>>(fQ, batch, bn1g, bn1b, fHC, NN);
    head_kernel<<<GG, 64, 0, stream>>>(fHC, fc1w, fc1b, bn2g, bn2b, fc2w, fc2b, out);
}

// Round 3
// 2953.600 us; speedup vs baseline: 1.7970x; 1.7970x over previous
//
#include <hip/hip_runtime.h>
#include <hip/hip_bf16.h>
#include <math.h>

#define NN 50000
#define EE 200000
#define ET 250000   // EE + NN self loops
#define GG 64
#define LL 6

using short8 = __attribute__((ext_vector_type(8))) short;
using f32x4  = __attribute__((ext_vector_type(4))) float;

__device__ __forceinline__ float elu1(float x) { return x > 0.f ? x : expm1f(x); }
__device__ __forceinline__ float gelu_exact(float x) {
    return 0.5f * x * (1.f + erff(x * 0.70710678118654752440f));
}
__device__ __forceinline__ short f2bf(float f) {
    __hip_bfloat16 h = __float2bfloat16(f);
    return *reinterpret_cast<short*>(&h);
}

// ---------------- CSR build ----------------
__global__ void count_deg_kernel(const int* __restrict__ ei, int* __restrict__ deg) {
    int e = blockIdx.x * 256 + threadIdx.x;
    if (e >= ET) return;
    int dst = (e < EE) ? ei[EE + e] : (e - EE);
    atomicAdd(&deg[dst], 1);
}

// thread-coarsened single-block exclusive scan (n=50000, 1024 threads x 49)
__global__ void scan_kernel(const int* __restrict__ deg, int* __restrict__ row_ptr, int n) {
    __shared__ int s[1024];
    int tid = threadIdx.x;
    const int per = (n + 1023) / 1024;
    int lo = tid * per, hi = min(lo + per, n);
    int sum = 0;
    for (int i = lo; i < hi; i++) sum += deg[i];
    s[tid] = sum;
    __syncthreads();
    for (int off = 1; off < 1024; off <<= 1) {
        int t = (tid >= off) ? s[tid - off] : 0;
        __syncthreads();
        s[tid] += t;
        __syncthreads();
    }
    int run = s[tid] - sum;   // exclusive prefix of this thread's range
    for (int i = lo; i < hi; i++) { row_ptr[i] = run; run += deg[i]; }
    if (tid == 1023) row_ptr[n] = s[1023];
}

__global__ void fill_csr_kernel(const int* __restrict__ ei, const int* __restrict__ row_ptr,
                                int* __restrict__ cursor, int* __restrict__ edge_src) {
    int e = blockIdx.x * 256 + threadIdx.x;
    if (e >= ET) return;
    int src, dst;
    if (e < EE) { src = ei[e]; dst = ei[EE + e]; }
    else        { src = e - EE; dst = e - EE; }
    int pos = atomicAdd(&cursor[dst], 1);
    edge_src[row_ptr[dst] + pos] = src;
}

__global__ void dinv_kernel(const int* __restrict__ row_ptr, float* __restrict__ dinv) {
    int n = blockIdx.x * 256 + threadIdx.x;
    if (n >= NN) return;
    int d = row_ptr[n + 1] - row_ptr[n];
    dinv[n] = (d > 0) ? rsqrtf((float)d) : 0.f;
}

// ---------------- weight prep: fp32 [K,N] (col-slice, ldb) -> bf16 MFMA B-fragment order
// Bp element ((c16*(K/32)+kb)*64 + l)*8 + j  ==  B[kb*32 + (l>>4)*8 + j][c16*16 + (l&15)]
__global__ void bprep_kernel(const float* __restrict__ B, short* __restrict__ Bp,
                             int K, int N, int ldb, long srcStride) {
    int layer = blockIdx.y;
    const float* Bsrc = B + srcStride * layer;
    short* Bd = Bp + (size_t)K * N * layer;
    int total = (K >> 5) * (N >> 4) * 64;
    int tid = blockIdx.x * 256 + threadIdx.x;
    if (tid >= total) return;
    int l = tid & 63;
    int rest = tid >> 6;
    int kbc = K >> 5;
    int kb = rest % kbc;
    int c16 = rest / kbc;
    int n = c16 * 16 + (l & 15);
    int kbase = kb * 32 + (l >> 4) * 8;
    short v[8];
#pragma unroll
    for (int j = 0; j < 8; j++) v[j] = f2bf(Bsrc[(size_t)(kbase + j) * ldb + n]);
    *(uint4*)(Bd + (size_t)tid * 8) = *(uint4*)v;
}

// ---------------- fp32 -> bf16 cast ----------------
__global__ void cast_bf16_kernel(const float* __restrict__ in, short* __restrict__ out, int n4) {
    int i = blockIdx.x * 256 + threadIdx.x;
    if (i >= n4) return;
    float4 v = *(const float4*)(in + (size_t)i * 4);
    short s[4] = { f2bf(v.x), f2bf(v.y), f2bf(v.z), f2bf(v.w) };
    *(uint2*)(out + (size_t)i * 4) = *(uint2*)s;
}

// ---------------- MFMA GEMM: C[M,Nc] = A[M,K](bf16) @ Bp(frag-packed bf16) -------
// 128x128 tile, BK=32, 256 thr = 4 waves, wave w does rows [w*32,w*32+32) x 128 cols.
template <bool BIAS, int ACT, bool OUTBF16, bool ASAD>
__global__ __launch_bounds__(256) void gemm_bf16_kernel(
    const short* __restrict__ A, const short* __restrict__ Bp,
    const float* __restrict__ bias, void* __restrict__ Cv,
    const float* __restrict__ a_s, const float* __restrict__ a_d,
    float* __restrict__ as_out, float* __restrict__ ad_out,
    int M, int K, int Nc) {
    __shared__ short As[128][40];   // +8 pad: row stride 80 B
    int t = threadIdx.x;
    int w = t >> 6, l = t & 63;
    int lq = l >> 4, ln = l & 15;
    int bm = blockIdx.x * 128, bn = blockIdx.y * 128;
    int kbc = K >> 5;
    f32x4 acc[2][8];
#pragma unroll
    for (int i = 0; i < 2; i++)
#pragma unroll
        for (int j = 0; j < 8; j++) acc[i][j] = (f32x4){0.f, 0.f, 0.f, 0.f};

    int ar = t >> 2;          // 0..63
    int ak = (t & 3) * 8;     // 0,8,16,24

    for (int kb = 0; kb < kbc; kb++) {
        int k0 = kb * 32;
        // stage A tile [128][32]
#pragma unroll
        for (int i = 0; i < 2; i++) {
            int r = ar + i * 64;
            int gr = bm + r;
            uint4 u = make_uint4(0, 0, 0, 0);
            if (gr < M) u = *(const uint4*)(A + (size_t)gr * K + k0 + ak);
            *(uint4*)&As[r][ak] = u;
        }
        __syncthreads();
        short8 af0 = *(const short8*)&As[w * 32 + ln][lq * 8];
        short8 af1 = *(const short8*)&As[w * 32 + 16 + ln][lq * 8];
#pragma unroll
        for (int ct = 0; ct < 8; ct++) {
            short8 bf = *(const short8*)(Bp + (((size_t)((bn >> 4) + ct) * kbc + kb) * 64 + l) * 8);
            acc[0][ct] = __builtin_amdgcn_mfma_f32_16x16x32_bf16(af0, bf, acc[0][ct], 0, 0, 0);
            acc[1][ct] = __builtin_amdgcn_mfma_f32_16x16x32_bf16(af1, bf, acc[1][ct], 0, 0, 0);
        }
        __syncthreads();
    }
    // ---- fused GAT score reduction (valid when Nc==128, bn==0) ----
    if (ASAD) {
#pragma unroll
        for (int rt = 0; rt < 2; rt++)
#pragma unroll
            for (int reg = 0; reg < 4; reg++) {
                float vs = 0.f, vd = 0.f;
#pragma unroll
                for (int ct = 0; ct < 8; ct++) {
                    float av = acc[rt][ct][reg];
                    int col = ct * 16 + ln;
                    vs += av * a_s[col];
                    vd += av * a_d[col];
                }
                for (int o = 8; o > 0; o >>= 1) { vs += __shfl_xor(vs, o); vd += __shfl_xor(vd, o); }
                int row = bm + w * 32 + rt * 16 + lq * 4 + reg;
                if (ln == 0 && row < M) { as_out[row] = vs; ad_out[row] = vd; }
            }
    }
    // ---- store C ----
#pragma unroll
    for (int ct = 0; ct < 8; ct++) {
        int col = bn + ct * 16 + ln;
        float bv_ = BIAS ? bias[col] : 0.f;
#pragma unroll
        for (int rt = 0; rt < 2; rt++)
#pragma unroll
            for (int reg = 0; reg < 4; reg++) {
                int row = bm + w * 32 + rt * 16 + lq * 4 + reg;
                if (row < M) {
                    float v = acc[rt][ct][reg] + bv_;
                    if (ACT == 1) v = gelu_exact(v);
                    if (OUTBF16)
                        ((__hip_bfloat16*)Cv)[(size_t)row * Nc + col] = __float2bfloat16(v);
                    else
                        ((float*)Cv)[(size_t)row * Nc + col] = v;
                }
            }
    }
}

// ---- GAT softmax-aggregate (LDS-staged edges, online softmax), bf16 col block out
__global__ __launch_bounds__(256) void gat_agg_c_kernel(
    const float* __restrict__ hpre, const float* __restrict__ as_,
    const float* __restrict__ ad_, const float* __restrict__ bias,
    const int* __restrict__ row_ptr, const int* __restrict__ edge_src,
    __hip_bfloat16* __restrict__ out, int ostride, int n_nodes) {
    __shared__ float sE[2][128];
    __shared__ int   sS[2][128];
    __shared__ int   sC[2];
    int slot = threadIdx.x >> 7;
    int node = blockIdx.x * 2 + slot;
    int c = threadIdx.x & 127;
    bool valid = node < n_nodes;
    int start = valid ? row_ptr[node] : 0;
    int deg   = valid ? row_ptr[node + 1] - start : 0;
    float adn = valid ? ad_[node] : 0.f;
    if (c == 0) sC[slot] = (deg + 127) >> 7;
    __syncthreads();
    int cmax = max(sC[0], sC[1]);
    float m = -1e30f, S = 0.f, acc = 0.f;
    for (int p = 0; p < cmax; p++) {
        int j0 = p * 128;
        int cnt = min(128, deg - j0);
        if (c < cnt) {
            int s = edge_src[start + j0 + c];
            float e = as_[s] + adn;
            sS[slot][c] = s;
            sE[slot][c] = e > 0.f ? e : 0.2f * e;
        }
        __syncthreads();
        if (cnt > 0) {
            float mc = m;
            for (int j = 0; j < cnt; j++) mc = fmaxf(mc, sE[slot][j]);
            float scale = expf(m - mc);
            S *= scale; acc *= scale;
            for (int j = 0; j < cnt; j++) {
                float wgt = expf(sE[slot][j] - mc);
                S += wgt;
                acc += wgt * hpre[(size_t)sS[slot][j] * 128 + c];
            }
            m = mc;
        }
        __syncthreads();
    }
    if (valid)
        out[(size_t)node * ostride + c] = __float2bfloat16(elu1(acc / (S + 1e-16f) + bias[c]));
}

// ---------------- GCN aggregation (LDS-staged) -> fp32 fQ + bf16 Qb -------------
__global__ __launch_bounds__(256) void gcn_agg_kernel(
    const float* __restrict__ hp, const float* __restrict__ dinv,
    const float* __restrict__ b3, const int* __restrict__ row_ptr,
    const int* __restrict__ edge_src, float* __restrict__ out,
    __hip_bfloat16* __restrict__ outb, int n_nodes) {
    __shared__ float sW[2][128];
    __shared__ int   sS[2][128];
    __shared__ int   sC[2];
    int slot = threadIdx.x >> 7;
    int node = blockIdx.x * 2 + slot;
    int c = threadIdx.x & 127;
    bool valid = node < n_nodes;
    int start = valid ? row_ptr[node] : 0;
    int deg   = valid ? row_ptr[node + 1] - start : 0;
    float dn  = valid ? dinv[node] : 0.f;
    if (c == 0) sC[slot] = (deg + 127) >> 7;
    __syncthreads();
    int cmax = max(sC[0], sC[1]);
    float acc = 0.f;
    for (int p = 0; p < cmax; p++) {
        int j0 = p * 128;
        int cnt = min(128, deg - j0);
        if (c < cnt) {
            int s = edge_src[start + j0 + c];
            sS[slot][c] = s;
            sW[slot][c] = dinv[s] * dn;
        }
        __syncthreads();
        for (int j = 0; j < cnt; j++)
            acc += sW[slot][j] * hp[(size_t)sS[slot][j] * 128 + c];
        __syncthreads();
    }
    if (valid) {
        float v = elu1(acc + b3[c]);
        out[(size_t)node * 128 + c] = v;
        outb[(size_t)node * 128 + c] = __float2bfloat16(v);
    }
}

// ---------------- residual + LayerNorm, fp32 in-place + bf16 copy ----------------
__global__ __launch_bounds__(256) void ln_residual_kernel(
    float* __restrict__ Q, __hip_bfloat16* __restrict__ Qb, const float* __restrict__ R,
    const float* __restrict__ g, const float* __restrict__ b, int n_nodes) {
    int node = blockIdx.x * 4 + (threadIdx.x >> 6);
    int lane = threadIdx.x & 63;
    if (node >= n_nodes) return;
    size_t base = (size_t)node * 128;
    float v0 = Q[base + lane] + R[base + lane];
    float v1 = Q[base + 64 + lane] + R[base + 64 + lane];
    float s = v0 + v1;
    for (int o = 32; o > 0; o >>= 1) s += __shfl_xor(s, o);
    float mean = s * (1.f / 128.f);
    float d0 = v0 - mean, d1 = v1 - mean;
    float vv = d0 * d0 + d1 * d1;
    for (int o = 32; o > 0; o >>= 1) vv += __shfl_xor(vv, o);
    float rstd = rsqrtf(vv * (1.f / 128.f) + 1e-5f);
    float o0 = d0 * rstd * g[lane] + b[lane];
    float o1 = d1 * rstd * g[lane + 64] + b[lane + 64];
    Q[base + lane] = o0;
    Q[base + 64 + lane] = o1;
    Qb[base + lane] = __float2bfloat16(o0);
    Qb[base + 64 + lane] = __float2bfloat16(o1);
}

// ---------------- pooling: stage 1 partials over 8 segments/graph ----------------
__global__ void pool1_kernel(const float* __restrict__ Q, const int* __restrict__ batch,
                             float* __restrict__ psum, float* __restrict__ pmax, int n_nodes) {
    int g = blockIdx.x, seg = blockIdx.y;
    int c = threadIdx.x;  // 128
    int lo, hi;
    {
        int l = 0, h = n_nodes;
        while (l < h) { int mid = (l + h) >> 1; if (batch[mid] < g) l = mid + 1; else h = mid; }
        lo = l;
        l = lo; h = n_nodes;
        while (l < h) { int mid = (l + h) >> 1; if (batch[mid] < g + 1) l = mid + 1; else h = mid; }
        hi = l;
    }
    int len = hi - lo;
    int a = lo + (int)((long)len * seg / 8);
    int b = lo + (int)((long)len * (seg + 1) / 8);
    float s = 0.f, mx = -INFINITY;
    for (int n = a; n < b; n++) {
        float v = Q[(size_t)n * 128 + c];
        s += v;
        mx = fmaxf(mx, v);
    }
    psum[(g * 8 + seg) * 128 + c] = s;
    pmax[(g * 8 + seg) * 128 + c] = mx;
}

__global__ void pool2_kernel(const float* __restrict__ psum, const float* __restrict__ pmax,
                             const int* __restrict__ batch,
                             const float* __restrict__ bn1g, const float* __restrict__ bn1b,
                             float* __restrict__ hc, int n_nodes) {
    int g = blockIdx.x;
    int c = threadIdx.x;  // 128
    int lo, hi;
    {
        int l = 0, h = n_nodes;
        while (l < h) { int mid = (l + h) >> 1; if (batch[mid] < g) l = mid + 1; else h = mid; }
        lo = l;
        l = lo; h = n_nodes;
        while (l < h) { int mid = (l + h) >> 1; if (batch[mid] < g + 1) l = mid + 1; else h = mid; }
        hi = l;
    }
    int cnt = hi - lo;
    float s = 0.f, mx = -INFINITY;
    for (int seg = 0; seg < 8; seg++) {
        s += psum[(g * 8 + seg) * 128 + c];
        mx = fmaxf(mx, pmax[(g * 8 + seg) * 128 + c]);
    }
    float hm = s / fmaxf((float)cnt, 1.f);
    float hx = (cnt > 0 && isfinite(mx)) ? mx : 0.f;
    const float bn_s = 0.99999500003749968f;  // 1/sqrt(1+1e-5)
    hc[g * 256 + c]       = hm * bn_s * bn1g[c] + bn1b[c];
    hc[g * 256 + 128 + c] = hx * bn_s * bn1g[128 + c] + bn1b[128 + c];
}

// ---------------- head: fc1+elu+bn2+fc2 ----------------
__global__ void head_kernel(const float* __restrict__ hc,
                            const float* __restrict__ fc1w, const float* __restrict__ fc1b,
                            const float* __restrict__ bn2g, const float* __restrict__ bn2b,
                            const float* __restrict__ fc2w, const float* __restrict__ fc2b,
                            float* __restrict__ out) {
    int g = blockIdx.x;
    int j = threadIdx.x;  // 64
    const float bn_s = 0.99999500003749968f;
    float acc = fc1b[j];
    for (int i = 0; i < 256; i++) acc += hc[g * 256 + i] * fc1w[i * 64 + j];
    acc = elu1(acc);
    acc = acc * bn_s * bn2g[j] + bn2b[j];
    __shared__ float sv[64];
    sv[j] = acc;
    __syncthreads();
    if (j < 2) {
        float o = fc2b[j];
        for (int i = 0; i < 64; i++) o += sv[i] * fc2w[i * 2 + j];
        out[g * 2 + j] = o;
    }
}

// ---------------- launch ----------------
extern "C" void kernel_launch(void* const* d_in, const int* in_sizes, int n_in,
                              void* d_out, int out_size, void* d_ws, size_t ws_size,
                              hipStream_t stream) {
    const float* x    = (const float*)d_in[0];
    const int*   ei   = (const int*)d_in[1];
    const int*   batch= (const int*)d_in[2];
    const float* W1   = (const float*)d_in[3];
    const float* as1  = (const float*)d_in[4];
    const float* ad1  = (const float*)d_in[5];
    const float* b1   = (const float*)d_in[6];
    const float* W2   = (const float*)d_in[7];
    const float* as2  = (const float*)d_in[8];
    const float* ad2  = (const float*)d_in[9];
    const float* b2   = (const float*)d_in[10];
    const float* W3   = (const float*)d_in[11];
    const float* b3   = (const float*)d_in[12];
    const float* wv   = (const float*)d_in[17];
    const float* bv   = (const float*)d_in[18];
    const float* wo   = (const float*)d_in[19];
    const float* bo   = (const float*)d_in[20];
    const float* ln1g = (const float*)d_in[21];
    const float* ln1b = (const float*)d_in[22];
    const float* ln2g = (const float*)d_in[23];
    const float* ln2b = (const float*)d_in[24];
    const float* wf1  = (const float*)d_in[25];
    const float* bf1  = (const float*)d_in[26];
    const float* wf2  = (const float*)d_in[27];
    const float* bf2  = (const float*)d_in[28];
    const float* bn1g = (const float*)d_in[29];
    const float* bn1b = (const float*)d_in[30];
    const float* fc1w = (const float*)d_in[31];
    const float* fc1b = (const float*)d_in[32];
    const float* bn2g = (const float*)d_in[33];
    const float* bn2b = (const float*)d_in[34];
    const float* fc2w = (const float*)d_in[35];
    const float* fc2b = (const float*)d_in[36];
    float* out = (float*)d_out;

    // ---- workspace layout (bytes), peak ~211 MB ----
    char* wsb = (char*)d_ws;
    short* bh1 = (short*)wsb;                           // [N,1024] bf16, GAT1 out
    short* Qb  = (short*)wsb;                           // [N,128] bf16 (bh1 dead)
    short* Vb  = (short*)(wsb + 12800000);              // [N,128] bf16
    short* FFb = (short*)(wsb + 25600000);              // [N,512] bf16
    short* bh2 = (short*)(wsb + 102400000);             // [N,512] bf16, GAT2 out
    short* xb  = (short*)(wsb + 102400000);             // [N,128] bf16 (pre-GAT2)
    float* fCh = (float*)(wsb + 153600000);             // [N,128] fp32 gemm out / fP
    float* fQ  = (float*)(wsb + 179200000);             // [N,128] fp32 transformer state
    char* tail = wsb + 204800000;
    short* W1p  = (short*)tail;                  tail += 262144;    // 8 x 128x128
    short* W2p  = (short*)tail;                  tail += 1048576;   // 4 x 1024x128
    short* W3p  = (short*)tail;                  tail += 131072;    // 512x128
    short* wvp  = (short*)tail;                  tail += 196608;    // 6 x 128x128
    short* wop  = (short*)tail;                  tail += 196608;
    short* wf1p = (short*)tail;                  tail += 786432;    // 6 x 128x512
    short* wf2p = (short*)tail;                  tail += 786432;    // 6 x 512x128
    float* fAS  = (float*)tail;                  tail += 200000;
    float* fAD  = (float*)tail;                  tail += 200000;
    float* fDv  = (float*)tail;                  tail += 200000;
    float* psum = (float*)tail;                  tail += 262144;    // 64x8x128
    float* pmax = (float*)tail;                  tail += 262144;
    float* fHC  = (float*)tail;                  tail += 65536;     // 64x256
    int* iDeg   = (int*)tail;                    tail += 200000;
    int* iRP    = (int*)tail;                    tail += 200004;
    int* iCur   = (int*)tail;                    tail += 200000;
    int* iES    = (int*)tail;                    tail += 1000000;

    hipMemsetAsync(iDeg, 0, NN * sizeof(int), stream);
    hipMemsetAsync(iCur, 0, NN * sizeof(int), stream);

    count_deg_kernel<<<(ET + 255) / 256, 256, 0, stream>>>(ei, iDeg);
    scan_kernel<<<1, 1024, 0, stream>>>(iDeg, iRP, NN);
    fill_csr_kernel<<<(ET + 255) / 256, 256, 0, stream>>>(ei, iRP, iCur, iES);
    dinv_kernel<<<(NN + 255) / 256, 256, 0, stream>>>(iRP, fDv);

    // weight prep (cast + fragment order)
    auto bprep = [&](const float* B, short* Bp, int K, int N, int ldb, long sStride, int layers) {
        int total = (K >> 5) * (N >> 4) * 64;
        dim3 grid((total + 255) / 256, layers);
        bprep_kernel<<<grid, 256, 0, stream>>>(B, Bp, K, N, ldb, sStride);
    };
    bprep(W1, W1p, 128, 128, 1024, 128, 8);       // per-head column slices
    bprep(W2, W2p, 1024, 128, 512, 128, 4);
    bprep(W3, W3p, 512, 128, 128, 0, 1);
    bprep(wv, wvp, 128, 128, 128, 16384, 6);
    bprep(wo, wop, 128, 128, 128, 16384, 6);
    bprep(wf1, wf1p, 128, 512, 512, 65536, 6);
    bprep(wf2, wf2p, 512, 128, 128, 65536, 6);
    cast_bf16_kernel<<<(NN * 128 / 4 + 255) / 256, 256, 0, stream>>>(x, xb, NN * 128 / 4);

    // ---- GAT layer 1: 8 heads ----
    for (int h = 0; h < 8; h++) {
        gemm_bf16_kernel<false, 0, false, true><<<dim3(391, 1), 256, 0, stream>>>(
            xb, W1p + h * 16384, nullptr, fCh, as1 + h * 128, ad1 + h * 128, fAS, fAD,
            NN, 128, 128);
        gat_agg_c_kernel<<<(NN + 1) / 2, 256, 0, stream>>>(
            fCh, fAS, fAD, b1 + h * 128, iRP, iES, (__hip_bfloat16*)(bh1 + h * 128), 1024, NN);
    }
    // ---- GAT layer 2: 4 heads ----
    for (int h = 0; h < 4; h++) {
        gemm_bf16_kernel<false, 0, false, true><<<dim3(391, 1), 256, 0, stream>>>(
            bh1, W2p + h * 131072, nullptr, fCh, as2 + h * 128, ad2 + h * 128, fAS, fAD,
            NN, 1024, 128);
        gat_agg_c_kernel<<<(NN + 1) / 2, 256, 0, stream>>>(
            fCh, fAS, fAD, b2 + h * 128, iRP, iES, (__hip_bfloat16*)(bh2 + h * 128), 512, NN);
    }
    // ---- GCN ----
    gemm_bf16_kernel<false, 0, false, false><<<dim3(391, 1), 256, 0, stream>>>(
        bh2, W3p, nullptr, fCh, nullptr, nullptr, nullptr, nullptr, NN, 512, 128);
    gcn_agg_kernel<<<(NN + 1) / 2, 256, 0, stream>>>(
        fCh, fDv, b3, iRP, iES, fQ, (__hip_bfloat16*)Qb, NN);
    // ---- Transformer (seq_len=1: attn == Wo(Wv h + bv) + bo) ----
    for (int l = 0; l < LL; l++) {
        gemm_bf16_kernel<true, 0, true, false><<<dim3(391, 1), 256, 0, stream>>>(
            Qb, wvp + l * 16384, bv + l * 128, Vb, nullptr, nullptr, nullptr, nullptr,
            NN, 128, 128);
        gemm_bf16_kernel<true, 0, false, false><<<dim3(391, 1), 256, 0, stream>>>(
            Vb, wop + l * 16384, bo + l * 128, fCh, nullptr, nullptr, nullptr, nullptr,
            NN, 128, 128);
        ln_residual_kernel<<<(NN + 3) / 4, 256, 0, stream>>>(
            fQ, (__hip_bfloat16*)Qb, fCh, ln1g + l * 128, ln1b + l * 128, NN);
        gemm_bf16_kernel<true, 1, true, false><<<dim3(391, 4), 256, 0, stream>>>(
            Qb, wf1p + l * 65536, bf1 + l * 512, FFb, nullptr, nullptr, nullptr, nullptr,
            NN, 128, 512);
        gemm_bf16_kernel<true, 0, false, false><<<dim3(391, 1), 256, 0, stream>>>(
            FFb, wf2p + l * 65536, bf2 + l * 128, fCh, nullptr, nullptr, nullptr, nullptr,
            NN, 512, 128);
        ln_residual_kernel<<<(NN + 3) / 4, 256, 0, stream>>>(
            fQ, (__hip_bfloat16*)Qb, fCh, ln2g + l * 128, ln2b + l * 128, NN);
    }
    // ---- pool + head ----
    pool1_kernel<<<dim3(GG, 8), 128, 0, stream>>>(fQ, batch, psum, pmax, NN);
    pool2_kernel<<<GG, 128, 0, stream>>>(psum, pmax, batch, bn1g, bn1b, fHC, NN);
    head_kernel<<<GG, 64, 0, stream>>>(fHC, fc1w, fc1b, bn2g, bn2b, fc2w, fc2b, out);
}

// Round 4
// 1555.583 us; speedup vs baseline: 3.4120x; 1.8987x over previous
//
#include <hip/hip_runtime.h>
#include <hip/hip_bf16.h>
#include <math.h>

#define NN 50000
#define EE 200000
#define ET 250000   // EE + NN self loops
#define GG 64
#define LL 6

using short8 = __attribute__((ext_vector_type(8))) short;
using f32x4  = __attribute__((ext_vector_type(4))) float;
typedef unsigned short ushortT;

__device__ __forceinline__ float elu1(float x) { return x > 0.f ? x : expm1f(x); }
__device__ __forceinline__ float gelu_exact(float x) {
    return 0.5f * x * (1.f + erff(x * 0.70710678118654752440f));
}
__device__ __forceinline__ short f2bf(float f) {
    __hip_bfloat16 h = __float2bfloat16(f);
    return *reinterpret_cast<short*>(&h);
}
__device__ __forceinline__ float bf2f(ushortT u) {
    return __uint_as_float(((unsigned)u) << 16);
}

// ---------------- CSR build ----------------
__global__ void count_deg_kernel(const int* __restrict__ ei, int* __restrict__ deg) {
    int e = blockIdx.x * 256 + threadIdx.x;
    if (e >= ET) return;
    int dst = (e < EE) ? ei[EE + e] : (e - EE);
    atomicAdd(&deg[dst], 1);
}

__global__ void scan_kernel(const int* __restrict__ deg, int* __restrict__ row_ptr, int n) {
    __shared__ int s[1024];
    int tid = threadIdx.x;
    const int per = (n + 1023) / 1024;
    int lo = tid * per, hi = min(lo + per, n);
    int sum = 0;
    for (int i = lo; i < hi; i++) sum += deg[i];
    s[tid] = sum;
    __syncthreads();
    for (int off = 1; off < 1024; off <<= 1) {
        int t = (tid >= off) ? s[tid - off] : 0;
        __syncthreads();
        s[tid] += t;
        __syncthreads();
    }
    int run = s[tid] - sum;
    for (int i = lo; i < hi; i++) { row_ptr[i] = run; run += deg[i]; }
    if (tid == 1023) row_ptr[n] = s[1023];
}

__global__ void fill_csr_kernel(const int* __restrict__ ei, const int* __restrict__ row_ptr,
                                int* __restrict__ cursor, int* __restrict__ edge_src) {
    int e = blockIdx.x * 256 + threadIdx.x;
    if (e >= ET) return;
    int src, dst;
    if (e < EE) { src = ei[e]; dst = ei[EE + e]; }
    else        { src = e - EE; dst = e - EE; }
    int pos = atomicAdd(&cursor[dst], 1);
    edge_src[row_ptr[dst] + pos] = src;
}

__global__ void dinv_kernel(const int* __restrict__ row_ptr, float* __restrict__ dinv) {
    int n = blockIdx.x * 256 + threadIdx.x;
    if (n >= NN) return;
    int d = row_ptr[n + 1] - row_ptr[n];
    dinv[n] = (d > 0) ? rsqrtf((float)d) : 0.f;
}

// ---- weight prep: fp32 [K,N] (ldb) -> bf16 MFMA B-fragment order ----
// Bp[((c16*(K/32)+kb)*64 + l)*8 + j] = B[kb*32 + (l>>4)*8 + j][c16*16 + (l&15)]
__global__ void bprep_kernel(const float* __restrict__ B, short* __restrict__ Bp,
                             int K, int N, int ldb, long srcStride) {
    int layer = blockIdx.y;
    const float* Bsrc = B + srcStride * layer;
    short* Bd = Bp + (size_t)K * N * layer;
    int total = (K >> 5) * (N >> 4) * 64;
    int tid = blockIdx.x * 256 + threadIdx.x;
    if (tid >= total) return;
    int l = tid & 63;
    int rest = tid >> 6;
    int kbc = K >> 5;
    int kb = rest % kbc;
    int c16 = rest / kbc;
    int n = c16 * 16 + (l & 15);
    int kbase = kb * 32 + (l >> 4) * 8;
    short v[8];
#pragma unroll
    for (int j = 0; j < 8; j++) v[j] = f2bf(Bsrc[(size_t)(kbase + j) * ldb + n]);
    *(uint4*)(Bd + (size_t)tid * 8) = *(uint4*)v;
}

__global__ void cast_bf16_kernel(const float* __restrict__ in, short* __restrict__ out, int n4) {
    int i = blockIdx.x * 256 + threadIdx.x;
    if (i >= n4) return;
    float4 v = *(const float4*)(in + (size_t)i * 4);
    short s[4] = { f2bf(v.x), f2bf(v.y), f2bf(v.z), f2bf(v.w) };
    *(uint2*)(out + (size_t)i * 4) = *(uint2*)s;
}

// ---------------- MFMA GEMM, LDS-free --------------------------------------
// C[M,Nc] = A[M,K](bf16) @ Bp(frag-packed). 64-row tiles (16 rows/wave), 128 cols.
// EPI: 0 plain, 1 gelu, 2 asad(+C), 3 residual+LN (Nc==128, writes Qout fp32 + Qbout bf16)
template <int EPI, bool BIAS, bool OUTBF16>
__global__ __launch_bounds__(256) void gemm_bf16_kernel(
    const short* __restrict__ A, const short* __restrict__ Bp,
    const float* __restrict__ bias, void* __restrict__ Cv,
    const float* __restrict__ a_s, const float* __restrict__ a_d,
    float* __restrict__ as_out, float* __restrict__ ad_out, int asH,
    const float* __restrict__ Rres, const float* __restrict__ lng,
    const float* __restrict__ lnb, float* __restrict__ Qout,
    __hip_bfloat16* __restrict__ Qbout,
    int M, int K, int Nc) {
    int t = threadIdx.x;
    int w = t >> 6, l = t & 63;
    int ln = l & 15, lq = l >> 4;
    int bm = blockIdx.x * 64 + w * 16;
    int bn = blockIdx.y * 128;
    int kbc = K >> 5;
    int cb0 = bn >> 4;

    int arow = bm + ln;
    bool aok = arow < M;
    const short* Ap = A + (size_t)arow * K + lq * 8;
    const short* Bpb = Bp + ((size_t)cb0 * kbc) * 512 + l * 8;

    f32x4 acc[8];
#pragma unroll
    for (int j = 0; j < 8; j++) acc[j] = (f32x4){0.f, 0.f, 0.f, 0.f};

    for (int kb = 0; kb < kbc; kb++) {
        short8 af = (short8){0,0,0,0,0,0,0,0};
        if (aok) af = *(const short8*)(Ap + kb * 32);
        const short* bpk = Bpb + (size_t)kb * 512;
#pragma unroll
        for (int ct = 0; ct < 8; ct++) {
            short8 bfr = *(const short8*)(bpk + (size_t)ct * kbc * 512);
            acc[ct] = __builtin_amdgcn_mfma_f32_16x16x32_bf16(af, bfr, acc[ct], 0, 0, 0);
        }
    }

    int rowb = bm + lq * 4;

    if (EPI == 2) {
        const float* asv = a_s + (bn >> 7) * 128;
        const float* adv = a_d + (bn >> 7) * 128;
#pragma unroll
        for (int reg = 0; reg < 4; reg++) {
            float vs = 0.f, vd = 0.f;
#pragma unroll
            for (int ct = 0; ct < 8; ct++) {
                int colL = ct * 16 + ln;
                float av = acc[ct][reg];
                vs += av * asv[colL];
                vd += av * adv[colL];
            }
            vs += __shfl_xor(vs, 1); vs += __shfl_xor(vs, 2);
            vs += __shfl_xor(vs, 4); vs += __shfl_xor(vs, 8);
            vd += __shfl_xor(vd, 1); vd += __shfl_xor(vd, 2);
            vd += __shfl_xor(vd, 4); vd += __shfl_xor(vd, 8);
            int row = rowb + reg;
            if (ln == 0 && row < M) {
                as_out[(size_t)row * asH + (bn >> 7)] = vs;
                ad_out[(size_t)row * asH + (bn >> 7)] = vd;
            }
        }
    }

    if (EPI == 3) {
        float v[8][4];
#pragma unroll
        for (int ct = 0; ct < 8; ct++) {
            int col = ct * 16 + ln;
            float bv_ = bias[col];
#pragma unroll
            for (int reg = 0; reg < 4; reg++) {
                int row = rowb + reg;
                float r = (row < M) ? Rres[(size_t)row * 128 + col] : 0.f;
                v[ct][reg] = acc[ct][reg] + bv_ + r;
            }
        }
#pragma unroll
        for (int reg = 0; reg < 4; reg++) {
            float s = 0.f;
#pragma unroll
            for (int ct = 0; ct < 8; ct++) s += v[ct][reg];
            s += __shfl_xor(s, 1); s += __shfl_xor(s, 2);
            s += __shfl_xor(s, 4); s += __shfl_xor(s, 8);
            float mean = s * (1.f / 128.f);
            float s2 = 0.f;
#pragma unroll
            for (int ct = 0; ct < 8; ct++) { float d = v[ct][reg] - mean; s2 += d * d; }
            s2 += __shfl_xor(s2, 1); s2 += __shfl_xor(s2, 2);
            s2 += __shfl_xor(s2, 4); s2 += __shfl_xor(s2, 8);
            float rstd = rsqrtf(s2 * (1.f / 128.f) + 1e-5f);
            int row = rowb + reg;
            if (row < M) {
#pragma unroll
                for (int ct = 0; ct < 8; ct++) {
                    int col = ct * 16 + ln;
                    float o = (v[ct][reg] - mean) * rstd * lng[col] + lnb[col];
                    Qout[(size_t)row * 128 + col] = o;
                    Qbout[(size_t)row * 128 + col] = __float2bfloat16(o);
                }
            }
        }
    } else {
#pragma unroll
        for (int ct = 0; ct < 8; ct++) {
            int col = bn + ct * 16 + ln;
            float bv_ = BIAS ? bias[col] : 0.f;
#pragma unroll
            for (int reg = 0; reg < 4; reg++) {
                int row = rowb + reg;
                if (row < M) {
                    float v = acc[ct][reg] + bv_;
                    if (EPI == 1) v = gelu_exact(v);
                    if (OUTBF16)
                        ((__hip_bfloat16*)Cv)[(size_t)row * Nc + col] = __float2bfloat16(v);
                    else
                        ((float*)Cv)[(size_t)row * Nc + col] = v;
                }
            }
        }
    }
}

// ---- fused multi-head GAT softmax-aggregate: one block per node ------------
template <int H, int CPT>
__global__ __launch_bounds__(256) void gat_agg_fused_kernel(
    const ushortT* __restrict__ hpre, const float* __restrict__ as_,
    const float* __restrict__ ad_, const float* __restrict__ bias,
    const int* __restrict__ row_ptr, const int* __restrict__ edge_src,
    __hip_bfloat16* __restrict__ out, int n_nodes) {
    int node = blockIdx.x;
    if (node >= n_nodes) return;
    int t = threadIdx.x;
    int c0 = t * CPT;
    int hb = c0 >> 7;
    int start = row_ptr[node];
    int deg = row_ptr[node + 1] - start;
    float adn = ad_[(size_t)node * H + hb];
    float m = -1e30f, S = 0.f;
    float acc[CPT];
#pragma unroll
    for (int c = 0; c < CPT; c++) acc[c] = 0.f;
    for (int j = 0; j < deg; j++) {
        int s = edge_src[start + j];
        float e = as_[(size_t)s * H + hb] + adn;
        e = e > 0.f ? e : 0.2f * e;
        float mn = fmaxf(m, e);
        float sc = expf(m - mn);
        float wj = expf(e - mn);
        S = S * sc + wj;
        const ushortT* hp = hpre + (size_t)s * (H * 128) + c0;
        float hv[CPT];
        if (CPT == 4) {
            uint2 u = *(const uint2*)hp;
            hv[0] = bf2f((ushortT)(u.x & 0xffff)); hv[1] = bf2f((ushortT)(u.x >> 16));
            hv[2] = bf2f((ushortT)(u.y & 0xffff)); hv[3] = bf2f((ushortT)(u.y >> 16));
        } else {
            unsigned u = *(const unsigned*)hp;
            hv[0] = bf2f((ushortT)(u & 0xffff)); hv[1] = bf2f((ushortT)(u >> 16));
        }
#pragma unroll
        for (int c = 0; c < CPT; c++) acc[c] = acc[c] * sc + wj * hv[c];
        m = mn;
    }
    float inv = 1.f / (S + 1e-16f);
#pragma unroll
    for (int c = 0; c < CPT; c++)
        out[(size_t)node * (H * 128) + c0 + c] =
            __float2bfloat16(elu1(acc[c] * inv + bias[c0 + c]));
}

// ---------------- GCN aggregation (bf16 in) -> fp32 fQ + bf16 Qb ------------
__global__ __launch_bounds__(256) void gcn_agg_kernel(
    const ushortT* __restrict__ hp, const float* __restrict__ dinv,
    const float* __restrict__ b3, const int* __restrict__ row_ptr,
    const int* __restrict__ edge_src, float* __restrict__ out,
    __hip_bfloat16* __restrict__ outb, int n_nodes) {
    int node = blockIdx.x * 2 + (threadIdx.x >> 7);
    int c = threadIdx.x & 127;
    if (node >= n_nodes) return;
    int start = row_ptr[node];
    int deg = row_ptr[node + 1] - start;
    float dn = dinv[node];
    float acc = 0.f;
    for (int j = 0; j < deg; j++) {
        int s = edge_src[start + j];
        acc += dinv[s] * dn * bf2f(hp[(size_t)s * 128 + c]);
    }
    float v = elu1(acc + b3[c]);
    out[(size_t)node * 128 + c] = v;
    outb[(size_t)node * 128 + c] = __float2bfloat16(v);
}

// ---------------- pooling ----------------
__global__ void pool1_kernel(const float* __restrict__ Q, const int* __restrict__ batch,
                             float* __restrict__ psum, float* __restrict__ pmax, int n_nodes) {
    int g = blockIdx.x, seg = blockIdx.y;
    int c = threadIdx.x;
    int lo, hi;
    {
        int l = 0, h = n_nodes;
        while (l < h) { int mid = (l + h) >> 1; if (batch[mid] < g) l = mid + 1; else h = mid; }
        lo = l;
        l = lo; h = n_nodes;
        while (l < h) { int mid = (l + h) >> 1; if (batch[mid] < g + 1) l = mid + 1; else h = mid; }
        hi = l;
    }
    int len = hi - lo;
    int a = lo + (int)((long)len * seg / 8);
    int b = lo + (int)((long)len * (seg + 1) / 8);
    float s = 0.f, mx = -INFINITY;
    for (int n = a; n < b; n++) {
        float v = Q[(size_t)n * 128 + c];
        s += v;
        mx = fmaxf(mx, v);
    }
    psum[(g * 8 + seg) * 128 + c] = s;
    pmax[(g * 8 + seg) * 128 + c] = mx;
}

__global__ void pool2_kernel(const float* __restrict__ psum, const float* __restrict__ pmax,
                             const int* __restrict__ batch,
                             const float* __restrict__ bn1g, const float* __restrict__ bn1b,
                             float* __restrict__ hc, int n_nodes) {
    int g = blockIdx.x;
    int c = threadIdx.x;
    int lo, hi;
    {
        int l = 0, h = n_nodes;
        while (l < h) { int mid = (l + h) >> 1; if (batch[mid] < g) l = mid + 1; else h = mid; }
        lo = l;
        l = lo; h = n_nodes;
        while (l < h) { int mid = (l + h) >> 1; if (batch[mid] < g + 1) l = mid + 1; else h = mid; }
        hi = l;
    }
    int cnt = hi - lo;
    float s = 0.f, mx = -INFINITY;
    for (int seg = 0; seg < 8; seg++) {
        s += psum[(g * 8 + seg) * 128 + c];
        mx = fmaxf(mx, pmax[(g * 8 + seg) * 128 + c]);
    }
    float hm = s / fmaxf((float)cnt, 1.f);
    float hx = (cnt > 0 && isfinite(mx)) ? mx : 0.f;
    const float bn_s = 0.99999500003749968f;
    hc[g * 256 + c]       = hm * bn_s * bn1g[c] + bn1b[c];
    hc[g * 256 + 128 + c] = hx * bn_s * bn1g[128 + c] + bn1b[128 + c];
}

__global__ void head_kernel(const float* __restrict__ hc,
                            const float* __restrict__ fc1w, const float* __restrict__ fc1b,
                            const float* __restrict__ bn2g, const float* __restrict__ bn2b,
                            const float* __restrict__ fc2w, const float* __restrict__ fc2b,
                            float* __restrict__ out) {
    int g = blockIdx.x;
    int j = threadIdx.x;
    const float bn_s = 0.99999500003749968f;
    float acc = fc1b[j];
    for (int i = 0; i < 256; i++) acc += hc[g * 256 + i] * fc1w[i * 64 + j];
    acc = elu1(acc);
    acc = acc * bn_s * bn2g[j] + bn2b[j];
    __shared__ float sv[64];
    sv[j] = acc;
    __syncthreads();
    if (j < 2) {
        float o = fc2b[j];
        for (int i = 0; i < 64; i++) o += sv[i] * fc2w[i * 2 + j];
        out[g * 2 + j] = o;
    }
}

// ---------------- launch ----------------
extern "C" void kernel_launch(void* const* d_in, const int* in_sizes, int n_in,
                              void* d_out, int out_size, void* d_ws, size_t ws_size,
                              hipStream_t stream) {
    const float* x    = (const float*)d_in[0];
    const int*   ei   = (const int*)d_in[1];
    const int*   batch= (const int*)d_in[2];
    const float* W1   = (const float*)d_in[3];
    const float* as1  = (const float*)d_in[4];
    const float* ad1  = (const float*)d_in[5];
    const float* b1   = (const float*)d_in[6];
    const float* W2   = (const float*)d_in[7];
    const float* as2  = (const float*)d_in[8];
    const float* ad2  = (const float*)d_in[9];
    const float* b2   = (const float*)d_in[10];
    const float* W3   = (const float*)d_in[11];
    const float* b3   = (const float*)d_in[12];
    const float* wv   = (const float*)d_in[17];
    const float* bv   = (const float*)d_in[18];
    const float* wo   = (const float*)d_in[19];
    const float* bo   = (const float*)d_in[20];
    const float* ln1g = (const float*)d_in[21];
    const float* ln1b = (const float*)d_in[22];
    const float* ln2g = (const float*)d_in[23];
    const float* ln2b = (const float*)d_in[24];
    const float* wf1  = (const float*)d_in[25];
    const float* bf1  = (const float*)d_in[26];
    const float* wf2  = (const float*)d_in[27];
    const float* bf2  = (const float*)d_in[28];
    const float* bn1g = (const float*)d_in[29];
    const float* bn1b = (const float*)d_in[30];
    const float* fc1w = (const float*)d_in[31];
    const float* fc1b = (const float*)d_in[32];
    const float* bn2g = (const float*)d_in[33];
    const float* bn2b = (const float*)d_in[34];
    const float* fc2w = (const float*)d_in[35];
    const float* fc2b = (const float*)d_in[36];
    float* out = (float*)d_out;

    // ---- workspace layout (bytes), peak ~227 MB ----
    char* wsb = (char*)d_ws;
    short* xb    = (short*)wsb;                        // [N,128] bf16  (region A)
    short* h1pre = (short*)(wsb + 12800000);           // [N,1024] bf16 (region B)
    short* h2pre = (short*)(wsb + 12800000);           // [N,512] bf16  (B, h1pre dead)
    short* h3pre = (short*)(wsb + 12800000);           // [N,128] bf16  (B, h2pre dead)
    short* FFb   = (short*)(wsb + 25600000);           // [N,512] bf16  (B tail)
    short* bh1   = (short*)(wsb + 115200000);          // [N,1024] bf16 (region C)
    short* bh2   = (short*)(wsb + 115200000);          // [N,512] bf16  (C, bh1 dead)
    short* Vb    = (short*)(wsb + 115200000);          // [N,128] bf16  (C, bh2 dead)
    float* fQ    = (float*)(wsb + 128000000);          // [N,128] fp32
    short* Qb    = (short*)(wsb + 153600000);          // [N,128] bf16
    char* tail = wsb + 217600000;
    short* W1p  = (short*)tail;  tail += 262144;       // 128x1024
    short* W2p  = (short*)tail;  tail += 1048576;      // 1024x512
    short* W3p  = (short*)tail;  tail += 131072;       // 512x128
    short* wvp  = (short*)tail;  tail += 196608;       // 6 x 128x128
    short* wop  = (short*)tail;  tail += 196608;
    short* wf1p = (short*)tail;  tail += 786432;       // 6 x 128x512
    short* wf2p = (short*)tail;  tail += 786432;       // 6 x 512x128
    float* fAS  = (float*)tail;  tail += 1600000;      // [N,8]
    float* fAD  = (float*)tail;  tail += 1600000;      // [N,8]
    float* fDv  = (float*)tail;  tail += 200000;
    float* psum = (float*)tail;  tail += 262144;
    float* pmax = (float*)tail;  tail += 262144;
    float* fHC  = (float*)tail;  tail += 65536;
    int* iDeg   = (int*)tail;    tail += 200000;
    int* iRP    = (int*)tail;    tail += 200004;
    int* iCur   = (int*)tail;    tail += 200000;
    int* iES    = (int*)tail;    tail += 1000000;

    hipMemsetAsync(iDeg, 0, NN * sizeof(int), stream);
    hipMemsetAsync(iCur, 0, NN * sizeof(int), stream);

    count_deg_kernel<<<(ET + 255) / 256, 256, 0, stream>>>(ei, iDeg);
    scan_kernel<<<1, 1024, 0, stream>>>(iDeg, iRP, NN);
    fill_csr_kernel<<<(ET + 255) / 256, 256, 0, stream>>>(ei, iRP, iCur, iES);
    dinv_kernel<<<(NN + 255) / 256, 256, 0, stream>>>(iRP, fDv);

    auto bprep = [&](const float* B, short* Bp, int K, int N, int ldb, long sStride, int layers) {
        int total = (K >> 5) * (N >> 4) * 64;
        dim3 grid((total + 255) / 256, layers);
        bprep_kernel<<<grid, 256, 0, stream>>>(B, Bp, K, N, ldb, sStride);
    };
    bprep(W1, W1p, 128, 1024, 1024, 0, 1);
    bprep(W2, W2p, 1024, 512, 512, 0, 1);
    bprep(W3, W3p, 512, 128, 128, 0, 1);
    bprep(wv, wvp, 128, 128, 128, 16384, 6);
    bprep(wo, wop, 128, 128, 128, 16384, 6);
    bprep(wf1, wf1p, 128, 512, 512, 65536, 6);
    bprep(wf2, wf2p, 512, 128, 128, 65536, 6);
    cast_bf16_kernel<<<(NN * 128 / 4 + 255) / 256, 256, 0, stream>>>(x, xb, NN * 128 / 4);

    const int MB = (NN + 63) / 64;   // 782

    // ---- GAT layer 1 (fused 8 heads) ----
    gemm_bf16_kernel<2, false, true><<<dim3(MB, 8), 256, 0, stream>>>(
        xb, W1p, nullptr, h1pre, as1, ad1, fAS, fAD, 8,
        nullptr, nullptr, nullptr, nullptr, nullptr, NN, 128, 1024);
    gat_agg_fused_kernel<8, 4><<<NN, 256, 0, stream>>>(
        (const ushortT*)h1pre, fAS, fAD, b1, iRP, iES, (__hip_bfloat16*)bh1, NN);
    // ---- GAT layer 2 (fused 4 heads) ----
    gemm_bf16_kernel<2, false, true><<<dim3(MB, 4), 256, 0, stream>>>(
        bh1, W2p, nullptr, h2pre, as2, ad2, fAS, fAD, 4,
        nullptr, nullptr, nullptr, nullptr, nullptr, NN, 1024, 512);
    gat_agg_fused_kernel<4, 2><<<NN, 256, 0, stream>>>(
        (const ushortT*)h2pre, fAS, fAD, b2, iRP, iES, (__hip_bfloat16*)bh2, NN);
    // ---- GCN ----
    gemm_bf16_kernel<0, false, true><<<dim3(MB, 1), 256, 0, stream>>>(
        bh2, W3p, nullptr, h3pre, nullptr, nullptr, nullptr, nullptr, 0,
        nullptr, nullptr, nullptr, nullptr, nullptr, NN, 512, 128);
    gcn_agg_kernel<<<(NN + 1) / 2, 256, 0, stream>>>(
        (const ushortT*)h3pre, fDv, b3, iRP, iES, fQ, (__hip_bfloat16*)Qb, NN);
    // ---- Transformer (seq_len=1: attn == Wo(Wv h + bv) + bo) ----
    for (int l = 0; l < LL; l++) {
        gemm_bf16_kernel<0, true, true><<<dim3(MB, 1), 256, 0, stream>>>(
            Qb, wvp + l * 16384, bv + l * 128, Vb, nullptr, nullptr, nullptr, nullptr, 0,
            nullptr, nullptr, nullptr, nullptr, nullptr, NN, 128, 128);
        gemm_bf16_kernel<3, true, false><<<dim3(MB, 1), 256, 0, stream>>>(
            Vb, wop + l * 16384, bo + l * 128, nullptr, nullptr, nullptr, nullptr, nullptr, 0,
            fQ, ln1g + l * 128, ln1b + l * 128, fQ, (__hip_bfloat16*)Qb, NN, 128, 128);
        gemm_bf16_kernel<1, true, true><<<dim3(MB, 4), 256, 0, stream>>>(
            Qb, wf1p + l * 65536, bf1 + l * 512, FFb, nullptr, nullptr, nullptr, nullptr, 0,
            nullptr, nullptr, nullptr, nullptr, nullptr, NN, 128, 512);
        gemm_bf16_kernel<3, true, false><<<dim3(MB, 1), 256, 0, stream>>>(
            FFb, wf2p + l * 65536, bf2 + l * 128, nullptr, nullptr, nullptr, nullptr, nullptr, 0,
            fQ, ln2g + l * 128, ln2b + l * 128, fQ, (__hip_bfloat16*)Qb, NN, 512, 128);
    }
    // ---- pool + head ----
    pool1_kernel<<<dim3(GG, 8), 128, 0, stream>>>(fQ, batch, psum, pmax, NN);
    pool2_kernel<<<GG, 128, 0, stream>>>(psum, pmax, batch, bn1g, bn1b, fHC, NN);
    head_kernel<<<GG, 64, 0, stream>>>(fHC, fc1w, fc1b, bn2g, bn2b, fc2w, fc2b, out);
}